// Round 13
// baseline (151.286 us; speedup 1.0000x reference)
//
#include <hip/hip_runtime.h>
#include <hip/hip_bf16.h>
#include <math.h>

#define BDIM 4
#define SLEN 4096
#define DDIM 1024
#define MROWS (BDIM*SLEN)      // 16384
#define KDIM DDIM              // 1024
#define NCHUNK 64
#define CLEN (SLEN/NCHUNK)     // 64
#define NCH (BDIM*DDIM)        // 4096
#define NKT (KDIM/32)          // 32 K-tiles (BK=32)
#define KBUF 32768             // per-K-tile LDS: A 16KB (8 tiles) + B 16KB (8 tiles)

typedef __bf16 bf16;
typedef __bf16 bf16x8 __attribute__((ext_vector_type(8)));
typedef float f32x16 __attribute__((ext_vector_type(16)));

__device__ __forceinline__ void gload_lds16(const void* g, void* l) {
  __builtin_amdgcn_global_load_lds(
      (const __attribute__((address_space(1))) unsigned int*)g,
      (__attribute__((address_space(3))) unsigned int*)l, 16, 0, 0);
}

// ---------------- cast f32 -> bf16 with fragment-order tile swizzle ----------
// [R8-verified] Tile = 32 rows x 32 k (2KB) at [T][KT]. Granule (r, j) stored
// at slot j*32 + r, so a 32x32x16 fragment read = base + lane*16 gives
// row = lane&31, k-granule = lane>>5. Reads coalesced; writes permute in 2KB.
__global__ void cast_swz_kernel(const float* __restrict__ in, bf16* __restrict__ out) {
  const int gid  = blockIdx.x * 256 + threadIdx.x;
  const int tile = gid >> 7, local = gid & 127;
  const int j = local & 3, r = local >> 2;     // coalesced read assignment
  const int T = tile >> 5, KT = tile & 31;
  const float4* src = (const float4*)(in + (size_t)(T*32 + r) * KDIM + KT*32 + j*8);
  float4 v0 = src[0], v1 = src[1];
  bf16x8 o;
  o[0] = (bf16)v0.x; o[1] = (bf16)v0.y; o[2] = (bf16)v0.z; o[3] = (bf16)v0.w;
  o[4] = (bf16)v1.x; o[5] = (bf16)v1.y; o[6] = (bf16)v1.z; o[7] = (bf16)v1.w;
  ((bf16x8*)out)[(size_t)tile * 128 + j*32 + r] = o;   // fragment-order slot
}

// ---------------- klam[h] = -C * softplus(-Lam[h]) ----------------
__global__ void klam_kernel(const float* __restrict__ Lam, float* __restrict__ klam) {
  int h = blockIdx.x * blockDim.x + threadIdx.x;
  if (h < DDIM) klam[h] = -8.0f * log1pf(__expf(-Lam[h]));
}

#define MFMA32(A,B,C) C = __builtin_amdgcn_mfma_f32_32x32x16_bf16(A, B, C, 0, 0, 0)

// ------------- 256x256 8-wave multi-phase dual GEMM + fused epilogue -------
// One tile = 256 m x (128 h x {Wa,Wx}). 8 waves (2M x 4N); per wave 128m x
// {32 Wa-cols + 32 Wx-cols at same h}. BK=32, 2 phases/K-tile, 4 LDS buffers
// (128KB), counted vmcnt(8) — never 0 in-loop. Per phase: 6 ds_read ->
// 2 gload_lds(t+3) -> barrier -> lgkmcnt(0) -> 8 MFMA (setprio) -> barrier.
__global__ __launch_bounds__(512, 2) void gemm_gates_kernel(
    const bf16* __restrict__ xb, const bf16* __restrict__ wab, const bf16* __restrict__ wxb,
    const float* __restrict__ ba, const float* __restrict__ bx,
    const float* __restrict__ klam, float* __restrict__ Aarr, bf16* __restrict__ Bp,
    float* __restrict__ sAo, float* __restrict__ sBo)
{
  __shared__ char smem[4*KBUF];   // 128 KB

  const int tid  = threadIdx.x;
  const int wave = tid >> 6, lane = tid & 63;
  const int wm = wave >> 2, wn = wave & 3;       // 2M x 4N

  // XCD-bijective swizzle: 512 blocks, 8 XCDs, 64 each.
  const int orig  = blockIdx.x;
  const int newid = (orig & 7) * 64 + (orig >> 3);
  const int m0 = (newid >> 3) * 256;
  const int h0 = (newid & 7) * 128;
  const int Tb = m0 >> 5;          // 8 x-row-tiles
  const int Hb = h0 >> 5;          // 4 w-row-tiles (per weight)

  f32x16 acc[4][2];
  #pragma unroll
  for (int i = 0; i < 4; i++) { acc[i][0] = (f32x16)0.0f; acc[i][1] = (f32x16)0.0f; }

  // ---- staging: per K-tile 4 rounds x 512 thr x 16B = 32KB ----
  const int tIdx = tid >> 7;            // 0..3
  const int g8   = (tid & 127) * 8;     // granule elem offset
  const int l16  = (tid & 127) * 16;    // granule byte offset
  const bf16* aS0 = xb  + (size_t)(Tb + tIdx)     * 32768 + g8;   // row-tiles 0-3
  const bf16* aS1 = xb  + (size_t)(Tb + 4 + tIdx) * 32768 + g8;   // row-tiles 4-7
  const bf16* bSa = wab + (size_t)(Hb + tIdx)     * 32768 + g8;   // Wa tiles 0-3
  const bf16* bSx = wxb + (size_t)(Hb + tIdx)     * 32768 + g8;   // Wx tiles 0-3
  const int dA0 = tIdx*2048 + l16;
  const int dA1 = (4 + tIdx)*2048 + l16;
  const int dBa = 16384 + tIdx*2048 + l16;
  const int dBx = 16384 + (4 + tIdx)*2048 + l16;

  auto SA = [&](int kt, char* b) {              // A half (2 loads)
    gload_lds16(aS0 + kt*1024, b + dA0);
    gload_lds16(aS1 + kt*1024, b + dA1);
  };
  auto SB = [&](int kt, char* b) {              // B half (2 loads)
    gload_lds16(bSa + kt*1024, b + dBa);
    gload_lds16(bSx + kt*1024, b + dBx);
  };

  // per-wave ds_read offsets (all base + lane*16 -> conflict-free)
  const int aOff = wm*8192 + lane*16;                 // + mi*2048 + kg*1024
  const int bOa  = 16384 + wn*2048 + lane*16;         // Wa tile wn
  const int bOx  = 16384 + (4 + wn)*2048 + lane*16;   // Wx tile wn

  char* p0 = smem;
  char* p1 = smem + KBUF;
  char* p2 = smem + 2*KBUF;
  char* p3 = smem + 3*KBUF;

  // prologue: 3 tiles in flight (12 loads/thread)
  SA(0, p0); SB(0, p0);
  SA(1, p1); SB(1, p1);
  SA(2, p2); SB(2, p2);
  asm volatile("s_waitcnt vmcnt(8)" ::: "memory");   // tile 0 landed (mine)
  __builtin_amdgcn_s_barrier();                      // all waves certified

  for (int t = 0; t < NKT; ++t) {
    const bool st = (t + 3 < NKT);
    // ======== phase 0 (kg = 0) ========
    bf16x8 a0 = *(const bf16x8*)(p0 + aOff);
    bf16x8 a1 = *(const bf16x8*)(p0 + aOff + 2048);
    bf16x8 a2 = *(const bf16x8*)(p0 + aOff + 4096);
    bf16x8 a3 = *(const bf16x8*)(p0 + aOff + 6144);
    bf16x8 bA = *(const bf16x8*)(p0 + bOa);
    bf16x8 bX = *(const bf16x8*)(p0 + bOx);
    __builtin_amdgcn_sched_barrier(0);
    if (st) SA(t + 3, p3);
    __builtin_amdgcn_s_barrier();                      // absorbs ds latency
    asm volatile("s_waitcnt lgkmcnt(0)" ::: "memory");
    __builtin_amdgcn_sched_barrier(0);                 // rule #18
    __builtin_amdgcn_s_setprio(1);
    MFMA32(a0, bA, acc[0][0]); MFMA32(a0, bX, acc[0][1]);
    MFMA32(a1, bA, acc[1][0]); MFMA32(a1, bX, acc[1][1]);
    MFMA32(a2, bA, acc[2][0]); MFMA32(a2, bX, acc[2][1]);
    MFMA32(a3, bA, acc[3][0]); MFMA32(a3, bX, acc[3][1]);
    __builtin_amdgcn_s_setprio(0);
    __builtin_amdgcn_s_barrier();

    // ======== phase 1 (kg = 1) ========
    a0 = *(const bf16x8*)(p0 + aOff + 1024);
    a1 = *(const bf16x8*)(p0 + aOff + 3072);
    a2 = *(const bf16x8*)(p0 + aOff + 5120);
    a3 = *(const bf16x8*)(p0 + aOff + 7168);
    bA = *(const bf16x8*)(p0 + bOa + 1024);
    bX = *(const bf16x8*)(p0 + bOx + 1024);
    __builtin_amdgcn_sched_barrier(0);
    if (st) SB(t + 3, p3);
    // counted cert for tile t+1 (outstanding: t+1,t+2[,t+3] = 8 or 12)
    if (t < NKT - 3)       { asm volatile("s_waitcnt vmcnt(8)" ::: "memory"); }
    else if (t == NKT - 3) { asm volatile("s_waitcnt vmcnt(4)" ::: "memory"); }
    else                   { asm volatile("s_waitcnt vmcnt(0)" ::: "memory"); }
    __builtin_amdgcn_s_barrier();
    asm volatile("s_waitcnt lgkmcnt(0)" ::: "memory");
    __builtin_amdgcn_sched_barrier(0);
    __builtin_amdgcn_s_setprio(1);
    MFMA32(a0, bA, acc[0][0]); MFMA32(a0, bX, acc[0][1]);
    MFMA32(a1, bA, acc[1][0]); MFMA32(a1, bX, acc[1][1]);
    MFMA32(a2, bA, acc[2][0]); MFMA32(a2, bX, acc[2][1]);
    MFMA32(a3, bA, acc[3][0]); MFMA32(a3, bX, acc[3][1]);
    __builtin_amdgcn_s_setprio(0);
    __builtin_amdgcn_s_barrier();

    char* tp = p0; p0 = p1; p1 = p2; p2 = p3; p3 = tp;   // rotate 4 buffers
  }

  // ---- epilogue ----
  // C/D (32x32): col = lane&31, row = (q&3) + 8*(q>>2) + 4*(lane>>5)
  const int colh = h0 + wn*32 + (lane & 31);
  const int hi   = lane >> 5;
  const float bah = ba[colh], bxh = bx[colh], kl = klam[colh];
  const size_t xh = (size_t)(colh >> 5) * 1024 + ((colh >> 3) & 3) * 256 + (colh & 7);

  #pragma unroll
  for (int c2 = 0; c2 < 2; ++c2) {            // two 64-row chunks per wave
    float P[2][4], S[2][4];
    #pragma unroll
    for (int ml = 0; ml < 2; ++ml) {
      const int mi    = c2*2 + ml;
      const int mbase = m0 + wm*128 + mi*32;
      const size_t xtb = (size_t)(mbase >> 5) * 32768 + xh;
      #pragma unroll
      for (int g = 0; g < 4; ++g) {
        float Pg = 1.0f, Sg = 0.0f;
        #pragma unroll
        for (int jj = 0; jj < 4; ++jj) {
          const int q   = g*4 + jj;
          const int row = jj + 8*g + 4*hi;
          const int m   = mbase + row;
          const float ga = acc[mi][0][q] + bah;
          const float gx = acc[mi][1][q] + bxh;
          const float rt = 1.0f / (1.0f + __expf(-ga));
          const float it = 1.0f / (1.0f + __expf(-gx));
          const float a  = __expf(kl * rt);
          const float xv = (float)xb[xtb + (size_t)row * 8];
          const float bb = sqrtf(fmaxf(1.0f - a*a, 0.0f)) * (it * xv);
          Aarr[(size_t)m * DDIM + colh] = a;        // a -> d_out (f32)
          Bp[(size_t)m * DDIM + colh]   = (bf16)bb; // b -> ws (bf16)
          Sg = fmaf(a, Sg, bb);
          Pg *= a;
        }
        P[ml][g] = Pg; S[ml][g] = Sg;
      }
    }
    // compose 16 segments in row order: sigma = ml*8 + g*2 + hi'
    float Pc = 1.0f, Sc = 0.0f;
    #pragma unroll
    for (int ml = 0; ml < 2; ++ml) {
      #pragma unroll
      for (int g = 0; g < 4; ++g) {
        const float pm = P[ml][g], sm = S[ml][g];
        const float pp = __shfl_xor(pm, 32);
        const float sp = __shfl_xor(sm, 32);
        const float p0v = hi ? pp : pm, s0v = hi ? sp : sm;
        const float p1v = hi ? pm : pp, s1v = hi ? sm : sp;
        Sc = fmaf(p0v, Sc, s0v); Pc *= p0v;
        Sc = fmaf(p1v, Sc, s1v); Pc *= p1v;
      }
    }
    if (hi == 0) {
      const int mb0  = m0 + wm*128 + c2*64;     // chunk start
      const int bidx = mb0 >> 12;
      const int c    = (mb0 & (SLEN-1)) >> 6;
      sAo[(size_t)c * NCH + bidx*1024 + colh] = Pc;
      sBo[(size_t)c * NCH + bidx*1024 + colh] = Sc;
    }
  }
}

// ---------------- phase 2: sequential prefix over chunks ----------------
__global__ void scan2_kernel(const float* __restrict__ sA, const float* __restrict__ sB,
                             float* __restrict__ Hin) {
  const int ch = blockIdx.x * 256 + threadIdx.x;
  float h = 0.0f;
  for (int c = 0; c < NCHUNK; ++c) {
    Hin[c * NCH + ch] = h;
    h = fmaf(sA[c * NCH + ch], h, sB[c * NCH + ch]);
  }
}

// ---------------- phase 3: apply (a lives in y == d_out; in-place) ----------
__global__ void scan3_kernel(const bf16* __restrict__ Bp, const float* __restrict__ Hin,
                             float* __restrict__ y) {
  const int ch = blockIdx.x * 256 + threadIdx.x;
  const int c  = blockIdx.y;
  const int b  = ch >> 10, d = ch & 1023;
  size_t idx = ((size_t)b * SLEN + (size_t)c * CLEN) * DDIM + d;
  float h = Hin[c * NCH + ch];
  #pragma unroll 4
  for (int s = 0; s < CLEN; ++s) {
    const float a = y[idx];                 // read a (same slot we overwrite)
    h = fmaf(a, h, (float)Bp[idx]);
    y[idx] = h;
    idx += DDIM;
  }
}

extern "C" void kernel_launch(void* const* d_in, const int* in_sizes, int n_in,
                              void* d_out, int out_size, void* d_ws, size_t ws_size,
                              hipStream_t stream) {
  const float* x   = (const float*)d_in[0];
  const float* Wa  = (const float*)d_in[1];
  const float* Wx  = (const float*)d_in[2];
  const float* ba  = (const float*)d_in[3];
  const float* bx  = (const float*)d_in[4];
  const float* Lam = (const float*)d_in[5];
  float* y = (float*)d_out;

  // workspace layout (bytes): total 74,452,992
  if (ws_size < 74452992ULL) return;  // insufficient scratch; fail cleanly
  char* ws = (char*)d_ws;
  bf16*  xb   = (bf16*)(ws);                     // 32 MB: x bf16, frag-order
  bf16*  wab  = (bf16*)(ws + 33554432);          //  2 MB, frag-order
  bf16*  wxb  = (bf16*)(ws + 35651584);          //  2 MB, frag-order
  bf16*  Bp   = (bf16*)(ws + 37748736);          // 32 MB: b (bf16)
  float* klam = (float*)(ws + 71303168);         //  4 KB
  float* sA   = (float*)(ws + 71307264);         //  1 MB
  float* sB   = (float*)(ws + 72355840);         //  1 MB
  float* Hin  = (float*)(ws + 73404416);         //  1 MB
  float* Aarr = y;                               // a lives in d_out, scan3 in-place

  cast_swz_kernel<<<(MROWS/32)*(KDIM/32)*128/256, 256, 0, stream>>>(x,  xb);
  cast_swz_kernel<<<(DDIM/32)*(KDIM/32)*128/256, 256, 0, stream>>>(Wa, wab);
  cast_swz_kernel<<<(DDIM/32)*(KDIM/32)*128/256, 256, 0, stream>>>(Wx, wxb);
  klam_kernel<<<DDIM/256, 256, 0, stream>>>(Lam, klam);

  // 512 blocks: (M/256) x (2048/256) = 64 x 8
  gemm_gates_kernel<<<512, 512, 0, stream>>>(xb, wab, wxb, ba, bx, klam,
                                             Aarr, Bp, sA, sB);

  scan2_kernel<<<NCH/256, 256, 0, stream>>>(sA, sB, Hin);
  dim3 sgrid(NCH/256, NCHUNK);
  scan3_kernel<<<sgrid, 256, 0, stream>>>(Bp, Hin, y);
}

// Round 14
// 140.939 us; speedup vs baseline: 1.0734x; 1.0734x over previous
//
#include <hip/hip_runtime.h>
#include <hip/hip_bf16.h>
#include <math.h>

#define BDIM 4
#define SLEN 4096
#define DDIM 1024
#define MROWS (BDIM*SLEN)      // 16384
#define KDIM DDIM              // 1024
#define NCHUNK 64
#define CLEN (SLEN/NCHUNK)     // 64
#define NCH (BDIM*DDIM)        // 4096
#define NKT (KDIM/32)          // 32 K-steps
#define LDSBUF 16384           // one buffer: X 8KB (4 tiles) + Wa 4KB + Wx 4KB
#define ALLROWS (MROWS + 2*DDIM)   // 18432 rows in fused cast

typedef __bf16 bf16;
typedef __bf16 bf16x8 __attribute__((ext_vector_type(8)));
typedef float f32x16 __attribute__((ext_vector_type(16)));

__device__ __forceinline__ void gload_lds16(const void* g, void* l) {
  __builtin_amdgcn_global_load_lds(
      (const __attribute__((address_space(1))) unsigned int*)g,
      (__attribute__((address_space(3))) unsigned int*)l, 16, 0, 0);
}

// ---------------- fused cast f32 -> bf16, fragment-order tile swizzle -------
// [R8-verified layout] Tile = 32 rows x 32 k (2KB) at [T][KT]; granule (r,j)
// at slot j*32 + r. Sources x / Wa / Wx concatenated by row (out buffers are
// ws-adjacent: xb | wab | wxb). Reads coalesced; writes permute within 2KB.
__global__ void cast_all_kernel(const float* __restrict__ x, const float* __restrict__ Wa,
                                const float* __restrict__ Wx, bf16* __restrict__ out) {
  const int gid  = blockIdx.x * 256 + threadIdx.x;
  const int tile = gid >> 7, local = gid & 127;
  const int j = local & 3, r = local >> 2;     // coalesced read assignment
  const int T = tile >> 5, KT = tile & 31;
  const int m = T*32 + r;
  const float* src;
  int row;
  if (m < MROWS)              { src = x;  row = m; }
  else if (m < MROWS + DDIM)  { src = Wa; row = m - MROWS; }
  else                        { src = Wx; row = m - MROWS - DDIM; }
  const float4* p = (const float4*)(src + (size_t)row * KDIM + KT*32 + j*8);
  float4 v0 = p[0], v1 = p[1];
  bf16x8 o;
  o[0] = (bf16)v0.x; o[1] = (bf16)v0.y; o[2] = (bf16)v0.z; o[3] = (bf16)v0.w;
  o[4] = (bf16)v1.x; o[5] = (bf16)v1.y; o[6] = (bf16)v1.z; o[7] = (bf16)v1.w;
  ((bf16x8*)out)[(size_t)tile * 128 + j*32 + r] = o;   // fragment-order slot
}

// ---------------- klam2[h] = -C * softplus(-Lam[h]) / ln2 ----------------
__global__ void klam_kernel(const float* __restrict__ Lam, float* __restrict__ klam) {
  int h = blockIdx.x * blockDim.x + threadIdx.x;
  if (h < DDIM) klam[h] = -8.0f * 1.4426950408889634f * log1pf(__expf(-Lam[h]));
}

// ---------------- dual-weight GEMM + gate epilogue + FUSED chunk summary ----
// [R12 main loop verbatim: 119.6us, 0 conflicts] Block 128(M) x 64(N), BK=32,
// 4 waves of 64x32-dual, 32x32x16 MFMA, 3 LDS buffers, 2 tiles in flight.
// Epilogue: la2 = klam2*sig(Ga) (bf16, a = 2^la2), b = sqrt(1-a^2)*sig(Gx)*x
// (bf16), plus the per-chunk scan summary (sA = prod a, sB = h with h0=0).
__global__ __launch_bounds__(256, 3) void gemm_gates_kernel(
    const bf16* __restrict__ xb, const bf16* __restrict__ wab, const bf16* __restrict__ wxb,
    const float* __restrict__ ba, const float* __restrict__ bx,
    const float* __restrict__ klam, bf16* __restrict__ La, bf16* __restrict__ Bp,
    float* __restrict__ sAo, float* __restrict__ sBo)
{
  __shared__ char smem[3*LDSBUF];   // 48 KB

  const int tid  = threadIdx.x;
  const int wave = tid >> 6, lane = tid & 63;
  const int wm = wave >> 1, wn = wave & 1;       // M split 2x64, N split 2x32

  // XCD-bijective swizzle: 2048 blocks, 8 XCDs, 256 each.
  const int orig  = blockIdx.x;
  const int newid = (orig & 7) * 256 + (orig >> 3);
  const int m0 = (newid >> 4) * 128;
  const int h0 = (newid & 15) * 64;

  f32x16 accA0 = (f32x16)0.0f, accA1 = (f32x16)0.0f;
  f32x16 accX0 = (f32x16)0.0f, accX1 = (f32x16)0.0f;

  const int Tb = m0 >> 5;           // first of 4 X row-tiles
  const int Ht = h0 >> 5;           // first of 2 W row-tiles
  const bf16* xsrc0 = xb  + (size_t)(Tb + (tid >> 7)) * 32768 + (tid & 127) * 8;
  const bf16* xsrc1 = xsrc0 + 2 * 32768;
  const bf16* wsrcA = wab + (size_t)(Ht + (tid >> 7)) * 32768 + (tid & 127) * 8;
  const bf16* wsrcX = wxb + (size_t)(Ht + (tid >> 7)) * 32768 + (tid & 127) * 8;

  auto STAGE = [&](int KT, char* nb) {
    gload_lds16(xsrc0 + KT*1024, nb + tid*16);            // X tiles 0,1
    gload_lds16(xsrc1 + KT*1024, nb + 4096  + tid*16);    // X tiles 2,3
    gload_lds16(wsrcA + KT*1024, nb + 8192  + tid*16);    // Wa tiles 0,1
    gload_lds16(wsrcX + KT*1024, nb + 12288 + tid*16);    // Wx tiles 0,1
  };

  const int awoff  = wm*4096  + lane*16;            // A: tiles wm*2, wm*2+1
  const int bwoffA = 8192  + wn*2048 + lane*16;     // Wa tile wn
  const int bwoffX = 12288 + wn*2048 + lane*16;     // Wx tile wn

  char* b0 = smem;
  char* b1 = smem + LDSBUF;
  char* b2 = smem + 2*LDSBUF;

  STAGE(0, b0);
  STAGE(1, b1);
  asm volatile("s_waitcnt vmcnt(4)" ::: "memory");   // tile 0 landed
  __builtin_amdgcn_s_barrier();

  char *pc = b0, *pn = b1, *ps = b2;
  for (int kt = 0; kt < NKT; ++kt) {
    // ---- phase 1: issue ds_reads for tile kt, then prefetch tile kt+2 ----
    bf16x8 a00 = *(const bf16x8*)(pc + awoff);            // mt0, k 0..16
    bf16x8 a01 = *(const bf16x8*)(pc + awoff + 1024);     // mt0, k 16..32
    bf16x8 a10 = *(const bf16x8*)(pc + awoff + 2048);     // mt1, k 0..16
    bf16x8 a11 = *(const bf16x8*)(pc + awoff + 3072);     // mt1, k 16..32
    bf16x8 ba0 = *(const bf16x8*)(pc + bwoffA);
    bf16x8 ba1 = *(const bf16x8*)(pc + bwoffA + 1024);
    bf16x8 bx0 = *(const bf16x8*)(pc + bwoffX);
    bf16x8 bx1 = *(const bf16x8*)(pc + bwoffX + 1024);
    __builtin_amdgcn_sched_barrier(0);                 // pin ds_reads here

    if (kt + 2 < NKT) STAGE(kt + 2, ps);

    __builtin_amdgcn_s_barrier();                      // rendezvous absorbs ds latency
    asm volatile("s_waitcnt lgkmcnt(0)" ::: "memory"); // ~free now
    __builtin_amdgcn_sched_barrier(0);                 // rule #18: no MFMA hoist

    __builtin_amdgcn_s_setprio(1);
    accA0 = __builtin_amdgcn_mfma_f32_32x32x16_bf16(a00, ba0, accA0, 0, 0, 0);
    accA1 = __builtin_amdgcn_mfma_f32_32x32x16_bf16(a10, ba0, accA1, 0, 0, 0);
    accX0 = __builtin_amdgcn_mfma_f32_32x32x16_bf16(a00, bx0, accX0, 0, 0, 0);
    accX1 = __builtin_amdgcn_mfma_f32_32x32x16_bf16(a10, bx0, accX1, 0, 0, 0);
    accA0 = __builtin_amdgcn_mfma_f32_32x32x16_bf16(a01, ba1, accA0, 0, 0, 0);
    accA1 = __builtin_amdgcn_mfma_f32_32x32x16_bf16(a11, ba1, accA1, 0, 0, 0);
    accX0 = __builtin_amdgcn_mfma_f32_32x32x16_bf16(a01, bx1, accX0, 0, 0, 0);
    accX1 = __builtin_amdgcn_mfma_f32_32x32x16_bf16(a11, bx1, accX1, 0, 0, 0);
    __builtin_amdgcn_s_setprio(0);

    // ---- end-of-step: ensure tile kt+1 fully landed for next step's reads ----
    if (kt + 2 < NKT)      { asm volatile("s_waitcnt vmcnt(4)" ::: "memory"); }
    else if (kt + 1 < NKT) { asm volatile("s_waitcnt vmcnt(0)" ::: "memory"); }
    if (kt + 1 < NKT) __builtin_amdgcn_s_barrier();

    char* tmp = pc; pc = pn; pn = ps; ps = tmp;
  }

  // ---- epilogue ----
  // C/D layout (32x32): col = lane&31, row = (q&3) + 8*(q>>2) + 4*(lane>>5)
  const int colh = h0 + wn*32 + (lane & 31);
  const int hi   = lane >> 5;
  const float bah = ba[colh], bxh = bx[colh], kl = klam[colh];  // kl pre-scaled by 1/ln2
  // x reload from fragment-order xb [R8-verified]
  const size_t xh = (size_t)(colh >> 5) * 1024 + ((colh >> 3) & 3) * 256 + (colh & 7);

  // segment maps: P/S over 4 consecutive rows (g-group), per mt and this hi.
  float P[2][4], S[2][4];
  #pragma unroll
  for (int mt = 0; mt < 2; ++mt) {
    const int mbase = m0 + wm*64 + mt*32;
    const size_t xtb = (size_t)(mbase >> 5) * 32768 + xh;
    const f32x16 aA = mt ? accA1 : accA0;
    const f32x16 aX = mt ? accX1 : accX0;
    #pragma unroll
    for (int g = 0; g < 4; ++g) {
      float Pg = 1.0f, Sg = 0.0f;
      #pragma unroll
      for (int jj = 0; jj < 4; ++jj) {
        const int q   = g*4 + jj;
        const int row = jj + 8*g + 4*hi;          // rows increase with jj
        const int m   = mbase + row;
        const float ga = aA[q] + bah;
        const float gx = aX[q] + bxh;
        const float rt = 1.0f / (1.0f + __expf(-ga));
        const float it = 1.0f / (1.0f + __expf(-gx));
        const float la = kl * rt;                 // log2(a)
        const float a  = exp2f(la);
        const float xv = (float)xb[xtb + (size_t)row * 8];
        const float bb = sqrtf(fmaxf(1.0f - a*a, 0.0f)) * (it * xv);
        La[(size_t)m * DDIM + colh] = (bf16)la;   // log2(a) -> ws (bf16)
        Bp[(size_t)m * DDIM + colh] = (bf16)bb;   // b -> ws (bf16)
        Sg = fmaf(a, Sg, bb);                     // exact a in the summary
        Pg *= a;
      }
      P[mt][g] = Pg; S[mt][g] = Sg;
    }
  }

  // compose the 16 segments in row order: sigma = mt*8 + g*2 + hi'
  float Pc = 1.0f, Sc = 0.0f;
  #pragma unroll
  for (int mt = 0; mt < 2; ++mt) {
    #pragma unroll
    for (int g = 0; g < 4; ++g) {
      const float pm = P[mt][g], sm = S[mt][g];
      const float pp = __shfl_xor(pm, 32);
      const float sp = __shfl_xor(sm, 32);
      const float p0 = hi ? pp : pm, s0 = hi ? sp : sm;   // hi'=0 first
      const float p1 = hi ? pm : pp, s1 = hi ? sm : sp;   // then hi'=1
      Sc = fmaf(p0, Sc, s0); Pc *= p0;
      Sc = fmaf(p1, Sc, s1); Pc *= p1;
    }
  }
  if (hi == 0) {
    const int mb0  = m0 + wm*64;          // chunk start (64-aligned)
    const int bidx = mb0 >> 12;           // batch
    const int c    = (mb0 & (SLEN-1)) >> 6;  // chunk within sequence
    sAo[(size_t)c * NCH + bidx*1024 + colh] = Pc;
    sBo[(size_t)c * NCH + bidx*1024 + colh] = Sc;
  }
}

// ---------------- phase 2: sequential prefix over chunks ----------------
__global__ void scan2_kernel(const float* __restrict__ sA, const float* __restrict__ sB,
                             float* __restrict__ Hin) {
  const int ch = blockIdx.x * 256 + threadIdx.x;
  float h = 0.0f;
  for (int c = 0; c < NCHUNK; ++c) {
    Hin[c * NCH + ch] = h;
    h = fmaf(sA[c * NCH + ch], h, sB[c * NCH + ch]);
  }
}

// ---------------- phase 3: apply (pure streaming; a = 2^la) ----------------
__global__ void scan3_kernel(const bf16* __restrict__ La, const bf16* __restrict__ Bp,
                             const float* __restrict__ Hin, float* __restrict__ y) {
  const int ch = blockIdx.x * 256 + threadIdx.x;
  const int c  = blockIdx.y;
  const int b  = ch >> 10, d = ch & 1023;
  size_t idx = ((size_t)b * SLEN + (size_t)c * CLEN) * DDIM + d;
  float h = Hin[c * NCH + ch];
  #pragma unroll 4
  for (int s = 0; s < CLEN; ++s) {
    const float a = exp2f((float)La[idx]);
    h = fmaf(a, h, (float)Bp[idx]);
    y[idx] = h;
    idx += DDIM;
  }
}

extern "C" void kernel_launch(void* const* d_in, const int* in_sizes, int n_in,
                              void* d_out, int out_size, void* d_ws, size_t ws_size,
                              hipStream_t stream) {
  const float* x   = (const float*)d_in[0];
  const float* Wa  = (const float*)d_in[1];
  const float* Wx  = (const float*)d_in[2];
  const float* ba  = (const float*)d_in[3];
  const float* bx  = (const float*)d_in[4];
  const float* Lam = (const float*)d_in[5];
  float* y = (float*)d_out;

  // workspace layout (bytes): total 108,007,424 (proven budget)
  if (ws_size < 108007424ULL) return;  // insufficient scratch; fail cleanly
  char* ws = (char*)d_ws;
  bf16*  xb   = (bf16*)(ws);                     // 32 MB: x bf16, frag-order
  bf16*  wab  = (bf16*)(ws + 33554432);          //  2 MB, frag-order (adjacent!)
  bf16*  wxb  = (bf16*)(ws + 35651584);          //  2 MB, frag-order (adjacent!)
  bf16*  Bp   = (bf16*)(ws + 37748736);          // 32 MB: b (bf16)
  bf16*  La   = (bf16*)(ws + 71303168);          // 32 MB: log2(a) (bf16)
  float* klam = (float*)(ws + 104857600);        //  4 KB (pre-scaled by 1/ln2)
  float* sA   = (float*)(ws + 104861696);        //  1 MB
  float* sB   = (float*)(ws + 105910272);        //  1 MB
  float* Hin  = (float*)(ws + 106958848);        //  1 MB

  // fused cast: 18432 rows x 1024 k -> 576 row-tiles x 32 k-tiles x 128 granules
  cast_all_kernel<<<(ALLROWS/32)*(KDIM/32)*128/256, 256, 0, stream>>>(x, Wa, Wx, xb);
  klam_kernel<<<DDIM/256, 256, 0, stream>>>(Lam, klam);

  // 2048 blocks: (M/128) * (N/64) = 128 * 16
  gemm_gates_kernel<<<2048, 256, 0, stream>>>(xb, wab, wxb, ba, bx, klam,
                                              La, Bp, sA, sB);

  scan2_kernel<<<NCH/256, 256, 0, stream>>>(sA, sB, Hin);
  dim3 sgrid(NCH/256, NCHUNK);
  scan3_kernel<<<sgrid, 256, 0, stream>>>(La, Bp, Hin, y);
}

// Round 15
// 140.789 us; speedup vs baseline: 1.0746x; 1.0011x over previous
//
#include <hip/hip_runtime.h>
#include <hip/hip_bf16.h>
#include <math.h>

#define BDIM 4
#define SLEN 4096
#define DDIM 1024
#define MROWS (BDIM*SLEN)      // 16384
#define KDIM DDIM              // 1024
#define NCHUNK 64
#define CLEN (SLEN/NCHUNK)     // 64
#define NCH (BDIM*DDIM)        // 4096
#define NKT (KDIM/32)          // 32 K-steps
#define LDSBUF 24576           // one buffer: X 16KB (8 tiles) + Wa 4KB + Wx 4KB
#define ALLROWS (MROWS + 2*DDIM)   // 18432 rows in fused cast

typedef __bf16 bf16;
typedef __bf16 bf16x8 __attribute__((ext_vector_type(8)));
typedef float f32x16 __attribute__((ext_vector_type(16)));

__device__ __forceinline__ void gload_lds16(const void* g, void* l) {
  __builtin_amdgcn_global_load_lds(
      (const __attribute__((address_space(1))) unsigned int*)g,
      (__attribute__((address_space(3))) unsigned int*)l, 16, 0, 0);
}

// ---------------- fused cast f32 -> bf16, fragment-order tile swizzle -------
// [R8-verified layout] Tile = 32 rows x 32 k (2KB) at [T][KT]; granule (r,j)
// at slot j*32 + r. Sources x / Wa / Wx concatenated by row (out buffers are
// ws-adjacent: xb | wab | wxb). Reads coalesced; writes permute within 2KB.
__global__ void cast_all_kernel(const float* __restrict__ x, const float* __restrict__ Wa,
                                const float* __restrict__ Wx, bf16* __restrict__ out) {
  const int gid  = blockIdx.x * 256 + threadIdx.x;
  const int tile = gid >> 7, local = gid & 127;
  const int j = local & 3, r = local >> 2;     // coalesced read assignment
  const int T = tile >> 5, KT = tile & 31;
  const int m = T*32 + r;
  const float* src;
  int row;
  if (m < MROWS)              { src = x;  row = m; }
  else if (m < MROWS + DDIM)  { src = Wa; row = m - MROWS; }
  else                        { src = Wx; row = m - MROWS - DDIM; }
  const float4* p = (const float4*)(src + (size_t)row * KDIM + KT*32 + j*8);
  float4 v0 = p[0], v1 = p[1];
  bf16x8 o;
  o[0] = (bf16)v0.x; o[1] = (bf16)v0.y; o[2] = (bf16)v0.z; o[3] = (bf16)v0.w;
  o[4] = (bf16)v1.x; o[5] = (bf16)v1.y; o[6] = (bf16)v1.z; o[7] = (bf16)v1.w;
  ((bf16x8*)out)[(size_t)tile * 128 + j*32 + r] = o;   // fragment-order slot
}

// ---------------- klam2[h] = -C * softplus(-Lam[h]) / ln2 ----------------
__global__ void klam_kernel(const float* __restrict__ Lam, float* __restrict__ klam) {
  int h = blockIdx.x * blockDim.x + threadIdx.x;
  if (h < DDIM) klam[h] = -8.0f * 1.4426950408889634f * log1pf(__expf(-Lam[h]));
}

// ---------------- dual-weight GEMM + gate epilogue + FUSED chunk summary ----
// 256(M) x 64(N)-dual block, 8 waves (4M x 2N), per-wave 64m x 32n-dual
// (identical per-wave shape to R12/R14: 8 ds_read : 8 MFMA 32x32x16 per
// K-step, acc = 64 regs). 3 LDS buffers x 24KB = 72KB -> 2 blocks/CU ->
// 4 waves/SIMD (vs 3). W staging halves: one W-load/thread; Wa/Wx LDS dest
// collapses to uniform 16384 + tid*16, source pointer wave-uniform select.
// Same verified phase ordering: {ds_reads ; STAGE(t+2)} -> barrier ->
// lgkmcnt(0) -> 8 MFMA -> vmcnt(3) -> barrier.
__global__ __launch_bounds__(512, 4) void gemm_gates_kernel(
    const bf16* __restrict__ xb, const bf16* __restrict__ wab, const bf16* __restrict__ wxb,
    const float* __restrict__ ba, const float* __restrict__ bx,
    const float* __restrict__ klam, bf16* __restrict__ La, bf16* __restrict__ Bp,
    float* __restrict__ sAo, float* __restrict__ sBo)
{
  __shared__ char smem[3*LDSBUF];   // 72 KB

  const int tid  = threadIdx.x;
  const int wave = tid >> 6, lane = tid & 63;
  const int wm = wave >> 1, wn = wave & 1;       // 4M x 2N waves

  // XCD-bijective swizzle: 1024 blocks, 8 XCDs, 128 each.
  const int orig  = blockIdx.x;
  const int newid = (orig & 7) * 128 + (orig >> 3);
  const int m0 = (newid >> 4) * 256;
  const int h0 = (newid & 15) * 64;

  f32x16 accA0 = (f32x16)0.0f, accA1 = (f32x16)0.0f;
  f32x16 accX0 = (f32x16)0.0f, accX1 = (f32x16)0.0f;

  const int Tb = m0 >> 5;           // first of 8 X row-tiles
  const int Ht = h0 >> 5;           // first of 2 W row-tiles (per weight)
  const int tt = tid >> 7;          // 0..3
  const int gg = (tid & 127) * 8;   // granule elem offset
  // X: thread stages granules tid (row-tiles 0-3) and tid+512 (row-tiles 4-7)
  const bf16* aS0 = xb + (size_t)(Tb + tt)     * 32768 + gg;
  const bf16* aS1 = xb + (size_t)(Tb + 4 + tt) * 32768 + gg;
  // W: threads 0-255 stage Wa (row-tiles 0,1), threads 256-511 stage Wx.
  // Dest is uniform 16384 + tid*16 (Wx region starts at 20480 = 16384+4096).
  const bf16* wS = (tid < 256)
      ? wab + (size_t)(Ht + tt)     * 32768 + gg
      : wxb + (size_t)(Ht + tt - 2) * 32768 + gg;

  auto STAGE = [&](int KT, char* nb) {
    gload_lds16(aS0 + KT*1024, nb + tid*16);            // X row-tiles 0-3
    gload_lds16(aS1 + KT*1024, nb + 8192 + tid*16);     // X row-tiles 4-7
    gload_lds16(wS  + KT*1024, nb + 16384 + tid*16);    // Wa | Wx
  };

  // per-wave ds_read offsets (all base + lane*16 -> conflict-free)
  const int aOff = wm*4096  + lane*16;              // subtiles 2wm, 2wm+1
  const int bOa  = 16384 + wn*2048 + lane*16;       // Wa tile wn
  const int bOx  = 20480 + wn*2048 + lane*16;       // Wx tile wn

  char* b0 = smem;
  char* b1 = smem + LDSBUF;
  char* b2 = smem + 2*LDSBUF;

  STAGE(0, b0);
  STAGE(1, b1);
  asm volatile("s_waitcnt vmcnt(3)" ::: "memory");   // tile 0 landed
  __builtin_amdgcn_s_barrier();

  char *pc = b0, *pn = b1, *ps = b2;
  for (int kt = 0; kt < NKT; ++kt) {
    // ---- phase 1: issue ds_reads for tile kt, then prefetch tile kt+2 ----
    bf16x8 a00 = *(const bf16x8*)(pc + aOff);            // subtile 2wm, kg0
    bf16x8 a01 = *(const bf16x8*)(pc + aOff + 1024);     // subtile 2wm, kg1
    bf16x8 a10 = *(const bf16x8*)(pc + aOff + 2048);     // subtile 2wm+1, kg0
    bf16x8 a11 = *(const bf16x8*)(pc + aOff + 3072);     // subtile 2wm+1, kg1
    bf16x8 ba0 = *(const bf16x8*)(pc + bOa);
    bf16x8 ba1 = *(const bf16x8*)(pc + bOa + 1024);
    bf16x8 bx0 = *(const bf16x8*)(pc + bOx);
    bf16x8 bx1 = *(const bf16x8*)(pc + bOx + 1024);
    __builtin_amdgcn_sched_barrier(0);                 // pin ds_reads here

    if (kt + 2 < NKT) STAGE(kt + 2, ps);

    __builtin_amdgcn_s_barrier();                      // rendezvous absorbs ds latency
    asm volatile("s_waitcnt lgkmcnt(0)" ::: "memory"); // ~free now
    __builtin_amdgcn_sched_barrier(0);                 // rule #18: no MFMA hoist

    __builtin_amdgcn_s_setprio(1);
    accA0 = __builtin_amdgcn_mfma_f32_32x32x16_bf16(a00, ba0, accA0, 0, 0, 0);
    accA1 = __builtin_amdgcn_mfma_f32_32x32x16_bf16(a10, ba0, accA1, 0, 0, 0);
    accX0 = __builtin_amdgcn_mfma_f32_32x32x16_bf16(a00, bx0, accX0, 0, 0, 0);
    accX1 = __builtin_amdgcn_mfma_f32_32x32x16_bf16(a10, bx0, accX1, 0, 0, 0);
    accA0 = __builtin_amdgcn_mfma_f32_32x32x16_bf16(a01, ba1, accA0, 0, 0, 0);
    accA1 = __builtin_amdgcn_mfma_f32_32x32x16_bf16(a11, ba1, accA1, 0, 0, 0);
    accX0 = __builtin_amdgcn_mfma_f32_32x32x16_bf16(a01, bx1, accX0, 0, 0, 0);
    accX1 = __builtin_amdgcn_mfma_f32_32x32x16_bf16(a11, bx1, accX1, 0, 0, 0);
    __builtin_amdgcn_s_setprio(0);

    // ---- end-of-step: ensure tile kt+1 fully landed for next step's reads ----
    if (kt + 2 < NKT)      { asm volatile("s_waitcnt vmcnt(3)" ::: "memory"); }
    else if (kt + 1 < NKT) { asm volatile("s_waitcnt vmcnt(0)" ::: "memory"); }
    if (kt + 1 < NKT) __builtin_amdgcn_s_barrier();

    char* tmp = pc; pc = pn; pn = ps; ps = tmp;
  }

  // ---- epilogue ----
  // C/D layout (32x32): col = lane&31, row = (q&3) + 8*(q>>2) + 4*(lane>>5)
  const int colh = h0 + wn*32 + (lane & 31);
  const int hi   = lane >> 5;
  const float bah = ba[colh], bxh = bx[colh], kl = klam[colh];  // kl pre-scaled by 1/ln2
  // x reload from fragment-order xb [R8-verified]
  const size_t xh = (size_t)(colh >> 5) * 1024 + ((colh >> 3) & 3) * 256 + (colh & 7);

  // segment maps: P/S over 4 consecutive rows (g-group), per mt and this hi.
  float P[2][4], S[2][4];
  #pragma unroll
  for (int mt = 0; mt < 2; ++mt) {
    const int mbase = m0 + wm*64 + mt*32;
    const size_t xtb = (size_t)(mbase >> 5) * 32768 + xh;
    const f32x16 aA = mt ? accA1 : accA0;
    const f32x16 aX = mt ? accX1 : accX0;
    #pragma unroll
    for (int g = 0; g < 4; ++g) {
      float Pg = 1.0f, Sg = 0.0f;
      #pragma unroll
      for (int jj = 0; jj < 4; ++jj) {
        const int q   = g*4 + jj;
        const int row = jj + 8*g + 4*hi;          // rows increase with jj
        const int m   = mbase + row;
        const float ga = aA[q] + bah;
        const float gx = aX[q] + bxh;
        const float rt = 1.0f / (1.0f + __expf(-ga));
        const float it = 1.0f / (1.0f + __expf(-gx));
        const float la = kl * rt;                 // log2(a)
        const float a  = exp2f(la);
        const float xv = (float)xb[xtb + (size_t)row * 8];
        const float bb = sqrtf(fmaxf(1.0f - a*a, 0.0f)) * (it * xv);
        La[(size_t)m * DDIM + colh] = (bf16)la;   // log2(a) -> ws (bf16)
        Bp[(size_t)m * DDIM + colh] = (bf16)bb;   // b -> ws (bf16)
        Sg = fmaf(a, Sg, bb);                     // exact a in the summary
        Pg *= a;
      }
      P[mt][g] = Pg; S[mt][g] = Sg;
    }
  }

  // compose the 16 segments in row order: sigma = mt*8 + g*2 + hi'
  float Pc = 1.0f, Sc = 0.0f;
  #pragma unroll
  for (int mt = 0; mt < 2; ++mt) {
    #pragma unroll
    for (int g = 0; g < 4; ++g) {
      const float pm = P[mt][g], sm = S[mt][g];
      const float pp = __shfl_xor(pm, 32);
      const float sp = __shfl_xor(sm, 32);
      const float p0 = hi ? pp : pm, s0 = hi ? sp : sm;   // hi'=0 first
      const float p1 = hi ? pm : pp, s1 = hi ? sm : sp;   // then hi'=1
      Sc = fmaf(p0, Sc, s0); Pc *= p0;
      Sc = fmaf(p1, Sc, s1); Pc *= p1;
    }
  }
  if (hi == 0) {
    const int mb0  = m0 + wm*64;          // chunk start (64-aligned)
    const int bidx = mb0 >> 12;           // batch
    const int c    = (mb0 & (SLEN-1)) >> 6;  // chunk within sequence
    sAo[(size_t)c * NCH + bidx*1024 + colh] = Pc;
    sBo[(size_t)c * NCH + bidx*1024 + colh] = Sc;
  }
}

// ---------------- phase 2: sequential prefix over chunks ----------------
__global__ void scan2_kernel(const float* __restrict__ sA, const float* __restrict__ sB,
                             float* __restrict__ Hin) {
  const int ch = blockIdx.x * 256 + threadIdx.x;
  float h = 0.0f;
  for (int c = 0; c < NCHUNK; ++c) {
    Hin[c * NCH + ch] = h;
    h = fmaf(sA[c * NCH + ch], h, sB[c * NCH + ch]);
  }
}

// ---------------- phase 3: apply (pure streaming; a = 2^la) ----------------
__global__ void scan3_kernel(const bf16* __restrict__ La, const bf16* __restrict__ Bp,
                             const float* __restrict__ Hin, float* __restrict__ y) {
  const int ch = blockIdx.x * 256 + threadIdx.x;
  const int c  = blockIdx.y;
  const int b  = ch >> 10, d = ch & 1023;
  size_t idx = ((size_t)b * SLEN + (size_t)c * CLEN) * DDIM + d;
  float h = Hin[c * NCH + ch];
  #pragma unroll 4
  for (int s = 0; s < CLEN; ++s) {
    const float a = exp2f((float)La[idx]);
    h = fmaf(a, h, (float)Bp[idx]);
    y[idx] = h;
    idx += DDIM;
  }
}

extern "C" void kernel_launch(void* const* d_in, const int* in_sizes, int n_in,
                              void* d_out, int out_size, void* d_ws, size_t ws_size,
                              hipStream_t stream) {
  const float* x   = (const float*)d_in[0];
  const float* Wa  = (const float*)d_in[1];
  const float* Wx  = (const float*)d_in[2];
  const float* ba  = (const float*)d_in[3];
  const float* bx  = (const float*)d_in[4];
  const float* Lam = (const float*)d_in[5];
  float* y = (float*)d_out;

  // workspace layout (bytes): total 108,007,424 (proven budget)
  if (ws_size < 108007424ULL) return;  // insufficient scratch; fail cleanly
  char* ws = (char*)d_ws;
  bf16*  xb   = (bf16*)(ws);                     // 32 MB: x bf16, frag-order
  bf16*  wab  = (bf16*)(ws + 33554432);          //  2 MB, frag-order (adjacent!)
  bf16*  wxb  = (bf16*)(ws + 35651584);          //  2 MB, frag-order (adjacent!)
  bf16*  Bp   = (bf16*)(ws + 37748736);          // 32 MB: b (bf16)
  bf16*  La   = (bf16*)(ws + 71303168);          // 32 MB: log2(a) (bf16)
  float* klam = (float*)(ws + 104857600);        //  4 KB (pre-scaled by 1/ln2)
  float* sA   = (float*)(ws + 104861696);        //  1 MB
  float* sB   = (float*)(ws + 105910272);        //  1 MB
  float* Hin  = (float*)(ws + 106958848);        //  1 MB

  // fused cast: 18432 rows x 1024 k -> 576 row-tiles x 32 k-tiles x 128 granules
  cast_all_kernel<<<(ALLROWS/32)*(KDIM/32)*128/256, 256, 0, stream>>>(x, Wa, Wx, xb);
  klam_kernel<<<DDIM/256, 256, 0, stream>>>(Lam, klam);

  // 1024 blocks: (M/256) * (N/64) = 64 * 16
  gemm_gates_kernel<<<1024, 512, 0, stream>>>(xb, wab, wxb, ba, bx, klam,
                                              La, Bp, sA, sB);

  scan2_kernel<<<NCH/256, 256, 0, stream>>>(sA, sB, Hin);
  dim3 sgrid(NCH/256, NCHUNK);
  scan3_kernel<<<sgrid, 256, 0, stream>>>(La, Bp, Hin, y);
}